// Round 1
// baseline (50.030 us; speedup 1.0000x reference)
//
#include <hip/hip_runtime.h>

#define BB 4
#define NN 16384
#define KK 16
#define DD 16
#define MTOT (BB*NN*KK)

// ws layout (floats):
// [0:16)    sum_dot[d]      (atomic accumulated, memset to 0 each launch)
// [16:32)   sumsq_dot[d]
// [32:160)  packed per-channel params, stride 8:
//           [d*8+0..2] = scale*(w_center + w_rel)   (x,y,z)
//           [d*8+3..5] = scale*(w_nb - w_rel)       (x,y,z)
//           [d*8+6]    = scale*w_dist
//           [d*8+7]    = bias2 = beta - mean_dot*scale   (conv_b cancels)

__global__ __launch_bounds__(256) void lse_stats(
    const float* __restrict__ coords,
    const int*   __restrict__ idx,
    const float* __restrict__ dist,
    const float* __restrict__ conv_w,
    float* __restrict__ ws)
{
    __shared__ __align__(16) float wl[DD*8];
    __shared__ float red[4][32];
    const int tid = threadIdx.x;
    if (tid < DD*8) {
        int d = tid >> 3, c = tid & 7;
        float v = 0.f;
        if (c < 3)      v = conv_w[d*10+c] + conv_w[d*10+6+c];   // center + rel
        else if (c < 6) v = conv_w[d*10+c] - conv_w[d*10+c+3];   // neighbor - rel
        else if (c == 6) v = conv_w[d*10+9];                     // dist
        wl[tid] = v;   // slot 7 = 0 (unused here)
    }
    __syncthreads();

    const int g = blockIdx.x * 256 + tid;   // one thread per (b,n); grid = B*N/256
    const int n = g & (NN - 1);
    const int b = g >> 14;

    const size_t cbase = (size_t)(b*NN + n) * 3;
    const float cx = coords[cbase+0], cy = coords[cbase+1], cz = coords[cbase+2];

    float ux[KK], uy[KK], uz[KK], ud[KK];
    const int4*   ip = (const int4*)  (idx  + (size_t)(b*NN + n) * KK);
    const float4* dp = (const float4*)(dist + (size_t)(b*NN + n) * KK);
    #pragma unroll
    for (int q = 0; q < 4; ++q) {
        int4  iv = ip[q];
        float4 dv = dp[q];
        int   js[4]  = {iv.x, iv.y, iv.z, iv.w};
        float dsv[4] = {dv.x, dv.y, dv.z, dv.w};
        #pragma unroll
        for (int t = 0; t < 4; ++t) {
            int k = q*4 + t;
            size_t nb = (size_t)(b*NN + js[t]) * 3;
            ux[k] = coords[nb+0];
            uy[k] = coords[nb+1];
            uz[k] = coords[nb+2];
            ud[k] = dsv[t];
        }
    }

    float sum[DD], ssq[DD];
    #pragma unroll
    for (int d = 0; d < DD; ++d) {
        float4 w0 = *(const float4*)&wl[d*8];
        float4 w1 = *(const float4*)&wl[d*8+4];
        float base = w0.x*cx + w0.y*cy + w0.z*cz;
        float s = 0.f, s2 = 0.f;
        #pragma unroll
        for (int k = 0; k < KK; ++k) {
            float dot = base + w0.w*ux[k] + w1.x*uy[k] + w1.y*uz[k] + w1.z*ud[k];
            s  += dot;
            s2  = fmaf(dot, dot, s2);
        }
        sum[d] = s; ssq[d] = s2;
    }

    // wave (64-lane) reduction of 32 scalars
    #pragma unroll
    for (int d = 0; d < DD; ++d) {
        float s = sum[d], s2 = ssq[d];
        for (int off = 32; off > 0; off >>= 1) {
            s  += __shfl_down(s,  off);
            s2 += __shfl_down(s2, off);
        }
        sum[d] = s; ssq[d] = s2;
    }
    const int lane = tid & 63, wave = tid >> 6;
    if (lane == 0) {
        #pragma unroll
        for (int d = 0; d < DD; ++d) { red[wave][d] = sum[d]; red[wave][16+d] = ssq[d]; }
    }
    __syncthreads();
    if (tid < 32) {
        float v = red[0][tid] + red[1][tid] + red[2][tid] + red[3][tid];
        atomicAdd(&ws[tid], v);
    }
}

__global__ void lse_finalize(
    const float* __restrict__ conv_w,
    const float* __restrict__ gamma,
    const float* __restrict__ beta,
    float* __restrict__ ws)
{
    __shared__ float sc_s[DD], b2_s[DD];
    const int tid = threadIdx.x;   // 128 threads
    if (tid < DD) {
        const float inv_m = 1.0f / (float)MTOT;
        float mean = ws[tid] * inv_m;
        float var  = ws[16+tid] * inv_m - mean*mean;
        float inv  = rsqrtf(var + 1e-6f);
        float sc   = gamma[tid] * inv;
        sc_s[tid] = sc;
        b2_s[tid] = beta[tid] - mean * sc;   // conv_b cancels exactly
    }
    __syncthreads();
    {
        int d = tid >> 3, c = tid & 7;
        float v = 0.f;
        if (c < 3)       v = conv_w[d*10+c] + conv_w[d*10+6+c];
        else if (c < 6)  v = conv_w[d*10+c] - conv_w[d*10+c+3];
        else if (c == 6) v = conv_w[d*10+9];
        ws[32 + tid] = (c == 7) ? b2_s[d] : v * sc_s[d];
    }
}

__global__ __launch_bounds__(256) void lse_write(
    const float* __restrict__ coords,
    const float* __restrict__ features,
    const int*   __restrict__ idx,
    const float* __restrict__ dist,
    const float* __restrict__ ws,
    float* __restrict__ out)
{
    __shared__ __align__(16) float wl[DD*8];
    const int tid = threadIdx.x;
    if (tid < DD*8) wl[tid] = ws[32 + tid];
    __syncthreads();

    const int g   = blockIdx.x * 256 + tid;  // one thread per (b,n,k-quad)
    const int kq  = g & 3;
    const int pos = g >> 2;
    const int n   = pos & (NN - 1);
    const int b   = pos >> 14;

    const size_t cbase = (size_t)(b*NN + n) * 3;
    const float cx = coords[cbase+0], cy = coords[cbase+1], cz = coords[cbase+2];

    const int4   iv = *(const int4*)  (idx  + ((size_t)(b*NN + n) * KK + kq*4));
    const float4 dv = *(const float4*)(dist + ((size_t)(b*NN + n) * KK + kq*4));

    float ux[4], uy[4], uz[4], ud[4];
    {
        int   js[4]  = {iv.x, iv.y, iv.z, iv.w};
        float dsv[4] = {dv.x, dv.y, dv.z, dv.w};
        #pragma unroll
        for (int t = 0; t < 4; ++t) {
            size_t nb = (size_t)(b*NN + js[t]) * 3;
            ux[t] = coords[nb+0];
            uy[t] = coords[nb+1];
            uz[t] = coords[nb+2];
            ud[t] = dsv[t];
        }
    }

    float* op = out + ((size_t)(b*2*DD) * NN + n) * KK + kq*4;

    #pragma unroll
    for (int d = 0; d < DD; ++d) {
        float4 w0 = *(const float4*)&wl[d*8];
        float4 w1 = *(const float4*)&wl[d*8+4];
        float base = w1.w + w0.x*cx + w0.y*cy + w0.z*cz;   // bias2 folded in
        float4 v;
        v.x = fmaxf(base + w0.w*ux[0] + w1.x*uy[0] + w1.y*uz[0] + w1.z*ud[0], 0.f);
        v.y = fmaxf(base + w0.w*ux[1] + w1.x*uy[1] + w1.y*uz[1] + w1.z*ud[1], 0.f);
        v.z = fmaxf(base + w0.w*ux[2] + w1.x*uy[2] + w1.y*uz[2] + w1.z*ud[2], 0.f);
        v.w = fmaxf(base + w0.w*ux[3] + w1.x*uy[3] + w1.y*uz[3] + w1.z*ud[3], 0.f);
        *(float4*)(op + (size_t)d * NN * KK) = v;
    }

    #pragma unroll
    for (int d = 0; d < DD; ++d) {
        float f = features[(size_t)(b*DD + d) * NN + n];
        float4 v = {f, f, f, f};
        *(float4*)(op + (size_t)(DD + d) * NN * KK) = v;
    }
}

extern "C" void kernel_launch(void* const* d_in, const int* in_sizes, int n_in,
                              void* d_out, int out_size, void* d_ws, size_t ws_size,
                              hipStream_t stream)
{
    const float* coords   = (const float*)d_in[0];
    const float* features = (const float*)d_in[1];
    const int*   idx      = (const int*)  d_in[2];
    const float* dist     = (const float*)d_in[3];
    const float* conv_w   = (const float*)d_in[4];
    // d_in[5] = conv_b: cancels exactly in batch-norm, unused
    const float* gamma    = (const float*)d_in[6];
    const float* beta     = (const float*)d_in[7];
    float* ws  = (float*)d_ws;
    float* out = (float*)d_out;

    hipMemsetAsync(d_ws, 0, 32 * sizeof(float), stream);
    lse_stats   <<<BB*NN/256,        256, 0, stream>>>(coords, idx, dist, conv_w, ws);
    lse_finalize<<<1,                128, 0, stream>>>(conv_w, gamma, beta, ws);
    lse_write   <<<BB*NN*KK/4/256,   256, 0, stream>>>(coords, features, idx, dist, ws, out);
}